// Round 9
// baseline (63.005 us; speedup 1.0000x reference)
//
#include <hip/hip_runtime.h>
#include <math.h>

#define N 8192
#define D 1024

typedef float f32x4 __attribute__((ext_vector_type(4)));

// Single fused kernel, 4096 blocks x 256 threads:
//   odd blocks  -> 4 row-dots each; publish raw[] via agent-scope coherent
//                  stores; winner election via device-scope atomicAdd walk
//                  ((old&2047)==2046 -> unique winner for ANY initial counter
//                  value, 0xAA-poison safe). Winner: softmax + diag scatter.
//   even blocks -> NT zero-fill in a GRID-STRIDE sweep (rocclr-style): at any
//                  instant all fill threads write one contiguous ~8 MB window,
//                  maximizing DRAM page/channel locality. Diagonal words are
//                  skipped (winner owns them).
__global__ __launch_bounds__(256) void fused_all(const float* __restrict__ q,
                                                 const float* __restrict__ k,
                                                 float* __restrict__ raw,
                                                 unsigned* __restrict__ counter,
                                                 float* __restrict__ out) {
    const int bid = blockIdx.x;
    const int t   = threadIdx.x;

    if (bid & 1) {
        // ---- dot role: rows 4*(bid>>1) .. +3 ----
        const int wave = t >> 6;
        const int lane = t & 63;
        const int row  = (bid >> 1) * 4 + wave;
        const float4* q4 = (const float4*)(q + (size_t)row * D);
        const float4* k4 = (const float4*)(k + (size_t)row * D);
        float s = 0.f;
        #pragma unroll
        for (int i = 0; i < 4; ++i) {          // D/4 = 256 float4s, 64 lanes -> 4 each
            float4 a = q4[lane + 64 * i];
            float4 b = k4[lane + 64 * i];
            s += a.x * b.x + a.y * b.y + a.z * b.z + a.w * b.w;
        }
        #pragma unroll
        for (int off = 32; off; off >>= 1) s += __shfl_down(s, off, 64);
        if (lane == 0)
            __hip_atomic_store(&raw[row], s, __ATOMIC_RELAXED,
                               __HIP_MEMORY_SCOPE_AGENT);   // coherent, no wbl2
        __syncthreads();                        // drains vmcnt before barrier

        __shared__ int win;
        if (t == 0) {
            unsigned old = atomicAdd(counter, 1u);          // device scope
            win = ((old & 2047u) == 2046u) ? 1 : 0;
        }
        __syncthreads();
        if (!win) return;

        // ---- winner: softmax over raw[8192] + diagonal scatter ----
        __threadfence();                        // single acquire fence
        const int lane2 = t & 63;
        const int wid   = t >> 6;               // 4 waves
        __shared__ float red[4];

        float v[32];
        float m = -INFINITY;
        #pragma unroll
        for (int i = 0; i < 32; ++i) {
            v[i] = __hip_atomic_load(&raw[t + 256 * i], __ATOMIC_RELAXED,
                                     __HIP_MEMORY_SCOPE_AGENT);
            m = fmaxf(m, v[i]);
        }
        #pragma unroll
        for (int off = 32; off; off >>= 1) m = fmaxf(m, __shfl_down(m, off, 64));
        if (lane2 == 0) red[wid] = m;
        __syncthreads();
        m = fmaxf(fmaxf(red[0], red[1]), fmaxf(red[2], red[3]));
        __syncthreads();

        float s2 = 0.f;
        #pragma unroll
        for (int i = 0; i < 32; ++i) {
            v[i] = __expf(v[i] - m);
            s2 += v[i];
        }
        #pragma unroll
        for (int off = 32; off; off >>= 1) s2 += __shfl_down(s2, off, 64);
        if (lane2 == 0) red[wid] = s2;
        __syncthreads();
        const float inv = 1.0f / (red[0] + red[1] + red[2] + red[3]);

        #pragma unroll
        for (int i = 0; i < 32; ++i) {
            const int r = t + 256 * i;
            out[(size_t)r * (N + 1)] = v[i] * inv;
        }
    } else {
        // ---- fill role: grid-stride sweep over 16M float4s ----
        // fill-thread id among 2048*256 = 524288 fill threads:
        const int ft = (bid >> 1) * 256 + t;
        f32x4* o4 = (f32x4*)out;
        const f32x4 z = {0.f, 0.f, 0.f, 0.f};
        #pragma unroll
        for (int i = 0; i < 32; ++i) {
            const int g4 = ft + (i << 19);      // float4 index in [0, 16M)
            const int r  = g4 >> 11;            // output row of this float4
            if ((g4 & 2047) == (r >> 2)) {
                // this float4 holds row r's diagonal word (col r, word r&3):
                // write the 3 non-diagonal words only (winner owns the 4th)
                const int j = r & 3;
                float* w = (float*)(o4 + g4);
                #pragma unroll
                for (int c = 0; c < 4; ++c)
                    if (c != j) __builtin_nontemporal_store(0.f, w + c);
            } else {
                __builtin_nontemporal_store(z, o4 + g4);
            }
        }
    }
}

extern "C" void kernel_launch(void* const* d_in, const int* in_sizes, int n_in,
                              void* d_out, int out_size, void* d_ws, size_t ws_size,
                              hipStream_t stream) {
    const float* q = (const float*)d_in[0];
    const float* k = (const float*)d_in[1];
    float* out = (float*)d_out;
    float* raw = (float*)d_ws;                            // 8192 floats
    unsigned* counter = (unsigned*)(raw + N);             // 1 uint, any init OK

    fused_all<<<4096, 256, 0, stream>>>(q, k, raw, counter, out);
}

// Round 10
// 59.679 us; speedup vs baseline: 1.0557x; 1.0557x over previous
//
#include <hip/hip_runtime.h>
#include <math.h>

#define N 8192
#define D 1024

typedef float f32x4 __attribute__((ext_vector_type(4)));

// Single fused kernel, 4096 blocks x 256 threads (R7 structure — best: 59.7us):
//   odd blocks  -> 4 row-dots each; publish raw[] via agent-scope coherent
//                  stores; winner election via device-scope atomicAdd walk
//                  ((old&2047)==2046 -> unique winner for ANY initial counter
//                  value, 0xAA-poison safe). Winner: softmax + diag scatter.
//   even blocks -> NT zero-fill of a CONTIGUOUS 128 KiB output slice
//                  (measured faster than grid-stride sweep), skipping the one
//                  diagonal word per row (winner owns those addresses).
__global__ __launch_bounds__(256) void fused_all(const float* __restrict__ q,
                                                 const float* __restrict__ k,
                                                 float* __restrict__ raw,
                                                 unsigned* __restrict__ counter,
                                                 float* __restrict__ out) {
    const int bid = blockIdx.x;
    const int t   = threadIdx.x;

    if (bid & 1) {
        // ---- dot role: rows 4*(bid>>1) .. +3 ----
        const int wave = t >> 6;
        const int lane = t & 63;
        const int row  = (bid >> 1) * 4 + wave;
        const float4* q4 = (const float4*)(q + (size_t)row * D);
        const float4* k4 = (const float4*)(k + (size_t)row * D);
        float s = 0.f;
        #pragma unroll
        for (int i = 0; i < 4; ++i) {          // D/4 = 256 float4s, 64 lanes -> 4 each
            float4 a = q4[lane + 64 * i];
            float4 b = k4[lane + 64 * i];
            s += a.x * b.x + a.y * b.y + a.z * b.z + a.w * b.w;
        }
        #pragma unroll
        for (int off = 32; off; off >>= 1) s += __shfl_down(s, off, 64);
        if (lane == 0)
            __hip_atomic_store(&raw[row], s, __ATOMIC_RELAXED,
                               __HIP_MEMORY_SCOPE_AGENT);   // coherent, no wbl2
        __syncthreads();                        // drains vmcnt before barrier

        __shared__ int win;
        if (t == 0) {
            unsigned old = atomicAdd(counter, 1u);          // device scope
            win = ((old & 2047u) == 2046u) ? 1 : 0;
        }
        __syncthreads();
        if (!win) return;

        // ---- winner: softmax over raw[8192] + diagonal scatter ----
        __threadfence();                        // single acquire fence
        const int lane2 = t & 63;
        const int wid   = t >> 6;               // 4 waves
        __shared__ float red[4];

        float v[32];
        float m = -INFINITY;
        #pragma unroll
        for (int i = 0; i < 32; ++i) {
            v[i] = __hip_atomic_load(&raw[t + 256 * i], __ATOMIC_RELAXED,
                                     __HIP_MEMORY_SCOPE_AGENT);
            m = fmaxf(m, v[i]);
        }
        #pragma unroll
        for (int off = 32; off; off >>= 1) m = fmaxf(m, __shfl_down(m, off, 64));
        if (lane2 == 0) red[wid] = m;
        __syncthreads();
        m = fmaxf(fmaxf(red[0], red[1]), fmaxf(red[2], red[3]));
        __syncthreads();

        float s2 = 0.f;
        #pragma unroll
        for (int i = 0; i < 32; ++i) {
            v[i] = __expf(v[i] - m);
            s2 += v[i];
        }
        #pragma unroll
        for (int off = 32; off; off >>= 1) s2 += __shfl_down(s2, off, 64);
        if (lane2 == 0) red[wid] = s2;
        __syncthreads();
        const float inv = 1.0f / (red[0] + red[1] + red[2] + red[3]);

        #pragma unroll
        for (int i = 0; i < 32; ++i) {
            const int r = t + 256 * i;
            out[(size_t)r * (N + 1)] = v[i] * inv;
        }
    } else {
        // ---- fill role: rows 4*fb .. 4*fb+3, 8192 float4s per block ----
        const int fb = bid >> 1;                // 0..2047
        f32x4* o4 = (f32x4*)out + (size_t)fb * 8192;
        const f32x4 z = {0.f, 0.f, 0.f, 0.f};
        #pragma unroll
        for (int i = 0; i < 32; ++i) {
            const int g = t + 256 * i;          // within-slice float4 index
            if ((g & 2047) == fb) {
                // this float4 holds the diagonal of row 4*fb + (g>>11):
                // write the 3 non-diagonal words only (winner owns the 4th)
                const int j = g >> 11;          // word to skip
                float* w = (float*)(o4 + g);
                #pragma unroll
                for (int c = 0; c < 4; ++c)
                    if (c != j) __builtin_nontemporal_store(0.f, w + c);
            } else {
                __builtin_nontemporal_store(z, o4 + g);
            }
        }
    }
}

extern "C" void kernel_launch(void* const* d_in, const int* in_sizes, int n_in,
                              void* d_out, int out_size, void* d_ws, size_t ws_size,
                              hipStream_t stream) {
    const float* q = (const float*)d_in[0];
    const float* k = (const float*)d_in[1];
    float* out = (float*)d_out;
    float* raw = (float*)d_ws;                            // 8192 floats
    unsigned* counter = (unsigned*)(raw + N);             // 1 uint, any init OK

    fused_all<<<4096, 256, 0, stream>>>(q, k, raw, counter, out);
}